// Round 1
// baseline (349.249 us; speedup 1.0000x reference)
//
#include <hip/hip_runtime.h>
#include <hip/hip_bf16.h>
#include <stdint.h>

#define K_DIM 1024
#define N_DIM 1024
#define BM 128
#define BN 128
#define BK 32

typedef __attribute__((ext_vector_type(8))) short short8;
typedef __attribute__((ext_vector_type(4))) float f32x4;

// ---- async global->LDS, 16B per lane (dest = wave-uniform base + lane*16) ----
__device__ __forceinline__ void gld16(const void* g, void* l) {
    __builtin_amdgcn_global_load_lds(
        (const __attribute__((address_space(1))) uint32_t*)(uintptr_t)g,
        (__attribute__((address_space(3))) uint32_t*)(uint32_t)(uintptr_t)l,
        16, 0, 0);
}

// pack two fp32 -> bf16x2 (round-half-up; |rel err| <= 2^-9)
__device__ __forceinline__ uint32_t pack2(float lo, float hi) {
    uint32_t a = __float_as_uint(lo) + 0x8000u;
    uint32_t b = __float_as_uint(hi) + 0x8000u;
    // result bytes: [a.b2, a.b3, b.b2, b.b3] -> (hi16(b)<<16)|hi16(a)
    return __builtin_amdgcn_perm(b, a, 0x07060302u);
}

// ---- stage 1: per-block |W| partial sums (fp64, deterministic) ----
__global__ void k_abs_partial(const float* __restrict__ W, double* __restrict__ part, int n4) {
    int stride = gridDim.x * blockDim.x;
    double s = 0.0;
    for (int i = blockIdx.x * blockDim.x + threadIdx.x; i < n4; i += stride) {
        float4 v = ((const float4*)W)[i];
        s += (double)fabsf(v.x) + (double)fabsf(v.y) + (double)fabsf(v.z) + (double)fabsf(v.w);
    }
    for (int o = 32; o > 0; o >>= 1) s += __shfl_down(s, o, 64);
    __shared__ double sm[4];
    int lane = threadIdx.x & 63, wv = threadIdx.x >> 6;
    if (lane == 0) sm[wv] = s;
    __syncthreads();
    if (threadIdx.x == 0) part[blockIdx.x] = sm[0] + sm[1] + sm[2] + sm[3];
}

// ---- stage 2: final reduce, store threshold = 0.5*mean(|W|) at ws[0] ----
__global__ void k_abs_final(double* __restrict__ ws) {
    double s = ws[8 + threadIdx.x];
    for (int o = 32; o > 0; o >>= 1) s += __shfl_down(s, o, 64);
    __shared__ double sm[4];
    int lane = threadIdx.x & 63, wv = threadIdx.x >> 6;
    if (lane == 0) sm[wv] = s;
    __syncthreads();
    if (threadIdx.x == 0)
        ws[0] = 0.5 * (sm[0] + sm[1] + sm[2] + sm[3]) / (double)(K_DIM * N_DIM);
}

// ---- stage 3: ternary quantize W -> bf16 {-1,0,+1} ----
__global__ void k_quant(const float* __restrict__ W, const double* __restrict__ thr,
                        ushort* __restrict__ wt, int n4) {
    float t = (float)thr[0];
    int i = blockIdx.x * blockDim.x + threadIdx.x;
    if (i >= n4) return;
    float4 v = ((const float4*)W)[i];
    ushort4 o;
    o.x = v.x > t ? 0x3F80u : (v.x < -t ? 0xBF80u : 0u);
    o.y = v.y > t ? 0x3F80u : (v.y < -t ? 0xBF80u : 0u);
    o.z = v.z > t ? 0x3F80u : (v.z < -t ? 0xBF80u : 0u);
    o.w = v.w > t ? 0x3F80u : (v.w < -t ? 0xBF80u : 0u);
    ((ushort4*)wt)[i] = o;
}

// ---- stage 4: GEMM  out[M,N] = x[M,K] @ wt[N,K]^T + b ----
// 256 thr = 4 waves (2x2), each wave 64x64 via 4x4 of 16x16x32 bf16 MFMA.
// A staged fp32 in LDS (XOR-swizzled 16B groups), converted to bf16 at frag read.
__global__ __launch_bounds__(256) void k_gemm(
    const float* __restrict__ x, const ushort* __restrict__ wt,
    const float* __restrict__ bias, float* __restrict__ out) {
    __shared__ __align__(16) float  As[BM * BK];   // 16 KB [m][k] (col-groups swizzled)
    __shared__ __align__(16) ushort Bs[BN * BK];   // 8 KB  [n][k]

    const int tid  = threadIdx.x;
    const int lane = tid & 63;
    const int wv   = tid >> 6;
    const int wm   = wv >> 1;
    const int wn   = wv & 1;
    const int r    = lane & 15;
    const int quad = lane >> 4;
    const int m0 = blockIdx.y * BM;
    const int n0 = blockIdx.x * BN;

    // A staging: per issue, 64 lanes cover 8 rows x 8 col-groups of 4 floats.
    // LDS slot (lane&7) holds global col-group (lane&7)^(row&7)  [XOR swizzle]
    const int arow = lane >> 3;                 // row within 8-row group
    const int ac4  = (lane & 7) ^ arow;         // swizzled global col-group
    const float* gA = x + (size_t)(m0 + wv * 32 + arow) * K_DIM + ac4 * 4;
    float* lA = As + (wv * 32) * BK;

    // B staging: per issue, 64 lanes cover 16 rows x 4 groups of 8 bf16. No swizzle.
    const int brow = lane >> 2;
    const int bc4  = lane & 3;
    const ushort* gB = wt + (size_t)(n0 + wv * 32 + brow) * K_DIM + bc4 * 8;
    ushort* lB = Bs + (wv * 32) * BK;

    f32x4 acc[4][4];
#pragma unroll
    for (int i = 0; i < 4; i++)
#pragma unroll
        for (int j = 0; j < 4; j++)
            acc[i][j] = (f32x4){0.f, 0.f, 0.f, 0.f};

    for (int k0 = 0; k0 < K_DIM; k0 += BK) {
#pragma unroll
        for (int i = 0; i < 4; i++)            // A: 4 issues x 1KB
            gld16(gA + (size_t)(i * 8) * K_DIM + k0, lA + (i * 8) * BK);
#pragma unroll
        for (int i = 0; i < 2; i++)            // B: 2 issues x 1KB
            gld16(gB + (size_t)(i * 16) * K_DIM + k0, lB + (i * 16) * BK);
        __syncthreads();                       // drains vmcnt before LDS reads

        short8 a[4], b[4];
#pragma unroll
        for (int nj = 0; nj < 4; nj++)
            b[nj] = *(const short8*)(Bs + (wn * 64 + nj * 16 + r) * BK + quad * 8);
#pragma unroll
        for (int mi = 0; mi < 4; mi++) {
            const float* pa = As + (wm * 64 + mi * 16 + r) * BK;
            const int g0 = ((quad * 2) ^ (r & 7)) * 4;      // swizzled slots
            const int g1 = ((quad * 2 + 1) ^ (r & 7)) * 4;
            float4 f0 = *(const float4*)(pa + g0);
            float4 f1 = *(const float4*)(pa + g1);
            union { short8 v; uint32_t u[4]; } pk;
            pk.u[0] = pack2(f0.x, f0.y);
            pk.u[1] = pack2(f0.z, f0.w);
            pk.u[2] = pack2(f1.x, f1.y);
            pk.u[3] = pack2(f1.z, f1.w);
            a[mi] = pk.v;
        }
#pragma unroll
        for (int mi = 0; mi < 4; mi++)
#pragma unroll
            for (int nj = 0; nj < 4; nj++)
                acc[mi][nj] = __builtin_amdgcn_mfma_f32_16x16x32_bf16(
                    a[mi], b[nj], acc[mi][nj], 0, 0, 0);
        __syncthreads();
    }

    // epilogue: C/D layout col=lane&15, row=quad*4+reg (m89-verified)
    float bv[4];
#pragma unroll
    for (int nj = 0; nj < 4; nj++) bv[nj] = bias[n0 + wn * 64 + nj * 16 + r];
#pragma unroll
    for (int mi = 0; mi < 4; mi++)
#pragma unroll
        for (int nj = 0; nj < 4; nj++) {
            const int col = n0 + wn * 64 + nj * 16 + r;
#pragma unroll
            for (int i = 0; i < 4; i++) {
                const int row = m0 + wm * 64 + mi * 16 + quad * 4 + i;
                out[(size_t)row * N_DIM + col] = acc[mi][nj][i] + bv[nj];
            }
        }
}

extern "C" void kernel_launch(void* const* d_in, const int* in_sizes, int n_in,
                              void* d_out, int out_size, void* d_ws, size_t ws_size,
                              hipStream_t stream) {
    const float* x = (const float*)d_in[0];
    const float* W = (const float*)d_in[1];
    const float* b = (const float*)d_in[2];
    float* out = (float*)d_out;
    double* wsd = (double*)d_ws;                       // ws[0]=threshold, ws[8..263]=partials
    ushort* wt = (ushort*)((char*)d_ws + 4096);        // 2 MB ternary bf16 [O,K]
    const int M = in_sizes[0] / K_DIM;                 // 32768

    const int n4 = (K_DIM * N_DIM) / 4;
    k_abs_partial<<<256, 256, 0, stream>>>(W, wsd + 8, n4);
    k_abs_final<<<1, 256, 0, stream>>>(wsd);
    k_quant<<<n4 / 256, 256, 0, stream>>>(W, wsd, wt, n4);
    dim3 grid(N_DIM / BN, M / BM);
    k_gemm<<<grid, 256, 0, stream>>>(x, wt, b, out);
}

// Round 2
// 331.564 us; speedup vs baseline: 1.0533x; 1.0533x over previous
//
#include <hip/hip_runtime.h>
#include <hip/hip_bf16.h>
#include <stdint.h>

#define K_DIM 1024
#define N_DIM 1024
#define BM 128
#define BN 128
#define BK 32

typedef __attribute__((ext_vector_type(8))) short short8;
typedef __attribute__((ext_vector_type(4))) float f32x4;

// ---- async global->LDS, 16B per lane (dest = wave-uniform base + lane*16) ----
__device__ __forceinline__ void gld16(const void* g, void* l) {
    __builtin_amdgcn_global_load_lds(
        (const __attribute__((address_space(1))) uint32_t*)(uintptr_t)g,
        (__attribute__((address_space(3))) uint32_t*)(uint32_t)(uintptr_t)l,
        16, 0, 0);
}

// pack two fp32 -> bf16x2 (round-half-up; |rel err| <= 2^-9)
__device__ __forceinline__ uint32_t pack2(float lo, float hi) {
    uint32_t a = __float_as_uint(lo) + 0x8000u;
    uint32_t b = __float_as_uint(hi) + 0x8000u;
    return __builtin_amdgcn_perm(b, a, 0x07060302u);
}

// ---- stage 1: per-block |W| partial sums (fp64, deterministic) ----
__global__ void k_abs_partial(const float* __restrict__ W, double* __restrict__ part, int n4) {
    int stride = gridDim.x * blockDim.x;
    double s = 0.0;
    for (int i = blockIdx.x * blockDim.x + threadIdx.x; i < n4; i += stride) {
        float4 v = ((const float4*)W)[i];
        s += (double)fabsf(v.x) + (double)fabsf(v.y) + (double)fabsf(v.z) + (double)fabsf(v.w);
    }
    for (int o = 32; o > 0; o >>= 1) s += __shfl_down(s, o, 64);
    __shared__ double sm[4];
    int lane = threadIdx.x & 63, wv = threadIdx.x >> 6;
    if (lane == 0) sm[wv] = s;
    __syncthreads();
    if (threadIdx.x == 0) part[blockIdx.x] = sm[0] + sm[1] + sm[2] + sm[3];
}

// ---- stage 2: final reduce, store threshold = 0.5*mean(|W|) at ws[0] ----
__global__ void k_abs_final(double* __restrict__ ws) {
    double s = ws[8 + threadIdx.x];
    for (int o = 32; o > 0; o >>= 1) s += __shfl_down(s, o, 64);
    __shared__ double sm[4];
    int lane = threadIdx.x & 63, wv = threadIdx.x >> 6;
    if (lane == 0) sm[wv] = s;
    __syncthreads();
    if (threadIdx.x == 0)
        ws[0] = 0.5 * (sm[0] + sm[1] + sm[2] + sm[3]) / (double)(K_DIM * N_DIM);
}

// ---- stage 3: ternary quantize W -> bf16 {-1,0,+1} ----
__global__ void k_quant(const float* __restrict__ W, const double* __restrict__ thr,
                        ushort* __restrict__ wt, int n4) {
    float t = (float)thr[0];
    int i = blockIdx.x * blockDim.x + threadIdx.x;
    if (i >= n4) return;
    float4 v = ((const float4*)W)[i];
    ushort4 o;
    o.x = v.x > t ? 0x3F80u : (v.x < -t ? 0xBF80u : 0u);
    o.y = v.y > t ? 0x3F80u : (v.y < -t ? 0xBF80u : 0u);
    o.z = v.z > t ? 0x3F80u : (v.z < -t ? 0xBF80u : 0u);
    o.w = v.w > t ? 0x3F80u : (v.w < -t ? 0xBF80u : 0u);
    ((ushort4*)wt)[i] = o;
}

// ---- stage 3b: convert x fp32 -> bf16 (8 floats/thread) ----
__global__ void k_cvt(const float* __restrict__ x, ushort* __restrict__ xb, int n8) {
    int i = blockIdx.x * blockDim.x + threadIdx.x;
    if (i >= n8) return;
    float4 f0 = ((const float4*)x)[i * 2];
    float4 f1 = ((const float4*)x)[i * 2 + 1];
    uint4 o;
    o.x = pack2(f0.x, f0.y);
    o.y = pack2(f0.z, f0.w);
    o.z = pack2(f1.x, f1.y);
    o.w = pack2(f1.z, f1.w);
    ((uint4*)xb)[i] = o;
}

// ---- stage 4 (fast path): pure-bf16 GEMM, m97 structure ----
// out[M,N] = xb[M,K] @ wt[N,K]^T + b. 256 thr = 4 waves (2x2), wave = 64x64
// via 4x4 of 16x16x32 bf16 MFMA. A,B bf16 in LDS, 8KB+8KB, gld16 staging.
__global__ __launch_bounds__(256) void k_gemm_bf16(
    const ushort* __restrict__ xb, const ushort* __restrict__ wt,
    const float* __restrict__ bias, float* __restrict__ out) {
    __shared__ __align__(16) ushort As[BM * BK];   // 8 KB [m][k]
    __shared__ __align__(16) ushort Bs[BN * BK];   // 8 KB [n][k]

    const int tid  = threadIdx.x;
    const int lane = tid & 63;
    const int wv   = tid >> 6;
    const int wm   = wv >> 1;
    const int wn   = wv & 1;
    const int r    = lane & 15;
    const int quad = lane >> 4;
    const int m0 = blockIdx.y * BM;
    const int n0 = blockIdx.x * BN;

    // staging: per issue, 64 lanes cover 16 rows x 4 groups of 8 bf16 (16B).
    // LDS order [row][k] contiguous == lane order (base + lane*16). No pad.
    const int srow = lane >> 2;        // 0..15
    const int sc   = (lane & 3) * 8;   // ushort offset in row
    const ushort* gA = xb + (size_t)(m0 + wv * 32 + srow) * K_DIM + sc;
    const ushort* gB = wt + (size_t)(n0 + wv * 32 + srow) * K_DIM + sc;
    ushort* lA = As + (wv * 32) * BK;
    ushort* lB = Bs + (wv * 32) * BK;

    f32x4 acc[4][4];
#pragma unroll
    for (int i = 0; i < 4; i++)
#pragma unroll
        for (int j = 0; j < 4; j++)
            acc[i][j] = (f32x4){0.f, 0.f, 0.f, 0.f};

    for (int k0 = 0; k0 < K_DIM; k0 += BK) {
#pragma unroll
        for (int i = 0; i < 2; i++) {  // 2 issues each of A and B per wave
            gld16(gA + (size_t)(i * 16) * K_DIM + k0, lA + (i * 16) * BK);
            gld16(gB + (size_t)(i * 16) * K_DIM + k0, lB + (i * 16) * BK);
        }
        __syncthreads();

        short8 a[4], b[4];
#pragma unroll
        for (int mi = 0; mi < 4; mi++)
            a[mi] = *(const short8*)(As + (wm * 64 + mi * 16 + r) * BK + quad * 8);
#pragma unroll
        for (int nj = 0; nj < 4; nj++)
            b[nj] = *(const short8*)(Bs + (wn * 64 + nj * 16 + r) * BK + quad * 8);
#pragma unroll
        for (int mi = 0; mi < 4; mi++)
#pragma unroll
            for (int nj = 0; nj < 4; nj++)
                acc[mi][nj] = __builtin_amdgcn_mfma_f32_16x16x32_bf16(
                    a[mi], b[nj], acc[mi][nj], 0, 0, 0);
        __syncthreads();
    }

    // epilogue: C/D layout col=lane&15, row=quad*4+reg (m89-verified)
    float bv[4];
#pragma unroll
    for (int nj = 0; nj < 4; nj++) bv[nj] = bias[n0 + wn * 64 + nj * 16 + r];
#pragma unroll
    for (int mi = 0; mi < 4; mi++)
#pragma unroll
        for (int nj = 0; nj < 4; nj++) {
            const int col = n0 + wn * 64 + nj * 16 + r;
#pragma unroll
            for (int i = 0; i < 4; i++) {
                const int row = m0 + wm * 64 + mi * 16 + quad * 4 + i;
                out[(size_t)row * N_DIM + col] = acc[mi][nj][i] + bv[nj];
            }
        }
}

// ---- stage 4 (fallback, small ws): fused fp32->bf16 conversion GEMM (round-1) ----
__global__ __launch_bounds__(256) void k_gemm_f32(
    const float* __restrict__ x, const ushort* __restrict__ wt,
    const float* __restrict__ bias, float* __restrict__ out) {
    __shared__ __align__(16) float  As[BM * BK];
    __shared__ __align__(16) ushort Bs[BN * BK];

    const int tid  = threadIdx.x;
    const int lane = tid & 63;
    const int wv   = tid >> 6;
    const int wm   = wv >> 1;
    const int wn   = wv & 1;
    const int r    = lane & 15;
    const int quad = lane >> 4;
    const int m0 = blockIdx.y * BM;
    const int n0 = blockIdx.x * BN;

    const int arow = lane >> 3;
    const int ac4  = (lane & 7) ^ arow;
    const float* gA = x + (size_t)(m0 + wv * 32 + arow) * K_DIM + ac4 * 4;
    float* lA = As + (wv * 32) * BK;

    const int brow = lane >> 2;
    const int bc4  = lane & 3;
    const ushort* gB = wt + (size_t)(n0 + wv * 32 + brow) * K_DIM + bc4 * 8;
    ushort* lB = Bs + (wv * 32) * BK;

    f32x4 acc[4][4];
#pragma unroll
    for (int i = 0; i < 4; i++)
#pragma unroll
        for (int j = 0; j < 4; j++)
            acc[i][j] = (f32x4){0.f, 0.f, 0.f, 0.f};

    for (int k0 = 0; k0 < K_DIM; k0 += BK) {
#pragma unroll
        for (int i = 0; i < 4; i++)
            gld16(gA + (size_t)(i * 8) * K_DIM + k0, lA + (i * 8) * BK);
#pragma unroll
        for (int i = 0; i < 2; i++)
            gld16(gB + (size_t)(i * 16) * K_DIM + k0, lB + (i * 16) * BK);
        __syncthreads();

        short8 a[4], b[4];
#pragma unroll
        for (int nj = 0; nj < 4; nj++)
            b[nj] = *(const short8*)(Bs + (wn * 64 + nj * 16 + r) * BK + quad * 8);
#pragma unroll
        for (int mi = 0; mi < 4; mi++) {
            const float* pa = As + (wm * 64 + mi * 16 + r) * BK;
            const int g0 = ((quad * 2) ^ (r & 7)) * 4;
            const int g1 = ((quad * 2 + 1) ^ (r & 7)) * 4;
            float4 f0 = *(const float4*)(pa + g0);
            float4 f1 = *(const float4*)(pa + g1);
            union { short8 v; uint32_t u[4]; } pk;
            pk.u[0] = pack2(f0.x, f0.y);
            pk.u[1] = pack2(f0.z, f0.w);
            pk.u[2] = pack2(f1.x, f1.y);
            pk.u[3] = pack2(f1.z, f1.w);
            a[mi] = pk.v;
        }
#pragma unroll
        for (int mi = 0; mi < 4; mi++)
#pragma unroll
            for (int nj = 0; nj < 4; nj++)
                acc[mi][nj] = __builtin_amdgcn_mfma_f32_16x16x32_bf16(
                    a[mi], b[nj], acc[mi][nj], 0, 0, 0);
        __syncthreads();
    }

    float bv[4];
#pragma unroll
    for (int nj = 0; nj < 4; nj++) bv[nj] = bias[n0 + wn * 64 + nj * 16 + r];
#pragma unroll
    for (int mi = 0; mi < 4; mi++)
#pragma unroll
        for (int nj = 0; nj < 4; nj++) {
            const int col = n0 + wn * 64 + nj * 16 + r;
#pragma unroll
            for (int i = 0; i < 4; i++) {
                const int row = m0 + wm * 64 + mi * 16 + quad * 4 + i;
                out[(size_t)row * N_DIM + col] = acc[mi][nj][i] + bv[nj];
            }
        }
}

extern "C" void kernel_launch(void* const* d_in, const int* in_sizes, int n_in,
                              void* d_out, int out_size, void* d_ws, size_t ws_size,
                              hipStream_t stream) {
    const float* x = (const float*)d_in[0];
    const float* W = (const float*)d_in[1];
    const float* b = (const float*)d_in[2];
    float* out = (float*)d_out;
    double* wsd = (double*)d_ws;                       // ws[0]=thr, ws[8..263]=partials
    ushort* wt = (ushort*)((char*)d_ws + 4096);        // 2 MB ternary bf16 [O,K]
    const int M = in_sizes[0] / K_DIM;                 // 32768

    const size_t XB_OFF = 4u * 1024 * 1024;            // x_bf16 at +4 MB
    const size_t WS_NEED = XB_OFF + (size_t)M * K_DIM * sizeof(ushort);
    ushort* xb = (ushort*)((char*)d_ws + XB_OFF);

    const int n4 = (K_DIM * N_DIM) / 4;
    k_abs_partial<<<256, 256, 0, stream>>>(W, wsd + 8, n4);
    k_abs_final<<<1, 256, 0, stream>>>(wsd);
    k_quant<<<n4 / 256, 256, 0, stream>>>(W, wsd, wt, n4);

    dim3 grid(N_DIM / BN, M / BM);
    if (ws_size >= WS_NEED) {
        const int n8 = M * K_DIM / 8;
        k_cvt<<<n8 / 256, 256, 0, stream>>>(x, xb, n8);
        k_gemm_bf16<<<grid, 256, 0, stream>>>(xb, wt, b, out);
    } else {
        k_gemm_f32<<<grid, 256, 0, stream>>>(x, wt, b, out);
    }
}

// Round 3
// 313.881 us; speedup vs baseline: 1.1127x; 1.0563x over previous
//
#include <hip/hip_runtime.h>
#include <hip/hip_bf16.h>
#include <stdint.h>

#define K_DIM 1024
#define N_DIM 1024
#define BM 128
#define BN 128
#define BK 32

typedef __attribute__((ext_vector_type(8))) short short8;
typedef __attribute__((ext_vector_type(4))) float f32x4;

// ---- async global->LDS, 16B per lane (dest = wave-uniform base + lane*16) ----
__device__ __forceinline__ void gld16(const void* g, void* l) {
    __builtin_amdgcn_global_load_lds(
        (const __attribute__((address_space(1))) uint32_t*)(uintptr_t)g,
        (__attribute__((address_space(3))) uint32_t*)(uint32_t)(uintptr_t)l,
        16, 0, 0);
}

// pack two fp32 -> bf16x2 (round-half-up; |rel err| <= 2^-9)
__device__ __forceinline__ uint32_t pack2(float lo, float hi) {
    uint32_t a = __float_as_uint(lo) + 0x8000u;
    uint32_t b = __float_as_uint(hi) + 0x8000u;
    return __builtin_amdgcn_perm(b, a, 0x07060302u);
}

// XCD-aware swizzle: consecutive linear IDs round-robin XCDs; give each XCD a
// contiguous 32-mb slab so the 8 blocks sharing an A-tile land on ONE XCD's L2.
__device__ __forceinline__ void block_map(int b, int& mb, int& nb) {
    int xcd = b & 7;
    int i = b >> 3;              // 0..255 within XCD
    mb = xcd * 32 + (i >> 3);    // 32 consecutive m-blocks per XCD
    nb = i & 7;
}

// ---- stage 1: per-block |W| partial sums (fp64, deterministic) ----
__global__ void k_abs_partial(const float* __restrict__ W, double* __restrict__ part, int n4) {
    int stride = gridDim.x * blockDim.x;
    double s = 0.0;
    for (int i = blockIdx.x * blockDim.x + threadIdx.x; i < n4; i += stride) {
        float4 v = ((const float4*)W)[i];
        s += (double)fabsf(v.x) + (double)fabsf(v.y) + (double)fabsf(v.z) + (double)fabsf(v.w);
    }
    for (int o = 32; o > 0; o >>= 1) s += __shfl_down(s, o, 64);
    __shared__ double sm[4];
    int lane = threadIdx.x & 63, wv = threadIdx.x >> 6;
    if (lane == 0) sm[wv] = s;
    __syncthreads();
    if (threadIdx.x == 0) part[blockIdx.x] = sm[0] + sm[1] + sm[2] + sm[3];
}

// ---- stage 2: final reduce, store threshold = 0.5*mean(|W|) at ws[0] ----
__global__ void k_abs_final(double* __restrict__ ws) {
    double s = ws[8 + threadIdx.x];
    for (int o = 32; o > 0; o >>= 1) s += __shfl_down(s, o, 64);
    __shared__ double sm[4];
    int lane = threadIdx.x & 63, wv = threadIdx.x >> 6;
    if (lane == 0) sm[wv] = s;
    __syncthreads();
    if (threadIdx.x == 0)
        ws[0] = 0.5 * (sm[0] + sm[1] + sm[2] + sm[3]) / (double)(K_DIM * N_DIM);
}

// ---- stage 3: ternary quantize W -> bf16 {-1,0,+1} ----
__global__ void k_quant(const float* __restrict__ W, const double* __restrict__ thr,
                        ushort* __restrict__ wt, int n4) {
    float t = (float)thr[0];
    int i = blockIdx.x * blockDim.x + threadIdx.x;
    if (i >= n4) return;
    float4 v = ((const float4*)W)[i];
    ushort4 o;
    o.x = v.x > t ? 0x3F80u : (v.x < -t ? 0xBF80u : 0u);
    o.y = v.y > t ? 0x3F80u : (v.y < -t ? 0xBF80u : 0u);
    o.z = v.z > t ? 0x3F80u : (v.z < -t ? 0xBF80u : 0u);
    o.w = v.w > t ? 0x3F80u : (v.w < -t ? 0xBF80u : 0u);
    ((ushort4*)wt)[i] = o;
}

// ---- stage 3b: convert x fp32 -> bf16 (8 floats/thread) ----
__global__ void k_cvt(const float* __restrict__ x, ushort* __restrict__ xb, int n8) {
    int i = blockIdx.x * blockDim.x + threadIdx.x;
    if (i >= n8) return;
    float4 f0 = ((const float4*)x)[i * 2];
    float4 f1 = ((const float4*)x)[i * 2 + 1];
    uint4 o;
    o.x = pack2(f0.x, f0.y);
    o.y = pack2(f0.z, f0.w);
    o.z = pack2(f1.x, f1.y);
    o.w = pack2(f1.z, f1.w);
    ((uint4*)xb)[i] = o;
}

// ---- stage 4 (fast path): pure-bf16 GEMM, m97 structure + XCD swizzle ----
__global__ __launch_bounds__(256) void k_gemm_bf16(
    const ushort* __restrict__ xb, const ushort* __restrict__ wt,
    const float* __restrict__ bias, float* __restrict__ out) {
    __shared__ __align__(16) ushort As[BM * BK];   // 8 KB [m][k]
    __shared__ __align__(16) ushort Bs[BN * BK];   // 8 KB [n][k]

    const int tid  = threadIdx.x;
    const int lane = tid & 63;
    const int wv   = tid >> 6;
    const int wm   = wv >> 1;
    const int wn   = wv & 1;
    const int r    = lane & 15;
    const int quad = lane >> 4;
    int mb, nb;
    block_map(blockIdx.x, mb, nb);
    const int m0 = mb * BM;
    const int n0 = nb * BN;

    const int srow = lane >> 2;        // 0..15
    const int sc   = (lane & 3) * 8;   // ushort offset in row
    const ushort* gA = xb + (size_t)(m0 + wv * 32 + srow) * K_DIM + sc;
    const ushort* gB = wt + (size_t)(n0 + wv * 32 + srow) * K_DIM + sc;
    ushort* lA = As + (wv * 32) * BK;
    ushort* lB = Bs + (wv * 32) * BK;

    f32x4 acc[4][4];
#pragma unroll
    for (int i = 0; i < 4; i++)
#pragma unroll
        for (int j = 0; j < 4; j++)
            acc[i][j] = (f32x4){0.f, 0.f, 0.f, 0.f};

    for (int k0 = 0; k0 < K_DIM; k0 += BK) {
#pragma unroll
        for (int i = 0; i < 2; i++) {
            gld16(gA + (size_t)(i * 16) * K_DIM + k0, lA + (i * 16) * BK);
            gld16(gB + (size_t)(i * 16) * K_DIM + k0, lB + (i * 16) * BK);
        }
        __syncthreads();

        short8 a[4], b[4];
#pragma unroll
        for (int mi = 0; mi < 4; mi++)
            a[mi] = *(const short8*)(As + (wm * 64 + mi * 16 + r) * BK + quad * 8);
#pragma unroll
        for (int nj = 0; nj < 4; nj++)
            b[nj] = *(const short8*)(Bs + (wn * 64 + nj * 16 + r) * BK + quad * 8);
#pragma unroll
        for (int mi = 0; mi < 4; mi++)
#pragma unroll
            for (int nj = 0; nj < 4; nj++)
                acc[mi][nj] = __builtin_amdgcn_mfma_f32_16x16x32_bf16(
                    a[mi], b[nj], acc[mi][nj], 0, 0, 0);
        __syncthreads();
    }

    // epilogue: C/D layout col=lane&15, row=quad*4+reg (m89-verified)
    float bv[4];
#pragma unroll
    for (int nj = 0; nj < 4; nj++) bv[nj] = bias[n0 + wn * 64 + nj * 16 + r];
#pragma unroll
    for (int mi = 0; mi < 4; mi++)
#pragma unroll
        for (int nj = 0; nj < 4; nj++) {
            const int col = n0 + wn * 64 + nj * 16 + r;
#pragma unroll
            for (int i = 0; i < 4; i++) {
                const int row = m0 + wm * 64 + mi * 16 + quad * 4 + i;
                out[(size_t)row * N_DIM + col] = acc[mi][nj][i] + bv[nj];
            }
        }
}

// ---- stage 4 (fallback, small ws): fused fp32->bf16 conversion GEMM ----
__global__ __launch_bounds__(256) void k_gemm_f32(
    const float* __restrict__ x, const ushort* __restrict__ wt,
    const float* __restrict__ bias, float* __restrict__ out) {
    __shared__ __align__(16) float  As[BM * BK];
    __shared__ __align__(16) ushort Bs[BN * BK];

    const int tid  = threadIdx.x;
    const int lane = tid & 63;
    const int wv   = tid >> 6;
    const int wm   = wv >> 1;
    const int wn   = wv & 1;
    const int r    = lane & 15;
    const int quad = lane >> 4;
    int mb, nb;
    block_map(blockIdx.x, mb, nb);
    const int m0 = mb * BM;
    const int n0 = nb * BN;

    const int arow = lane >> 3;
    const int ac4  = (lane & 7) ^ arow;
    const float* gA = x + (size_t)(m0 + wv * 32 + arow) * K_DIM + ac4 * 4;
    float* lA = As + (wv * 32) * BK;

    const int brow = lane >> 2;
    const int bc4  = lane & 3;
    const ushort* gB = wt + (size_t)(n0 + wv * 32 + brow) * K_DIM + bc4 * 8;
    ushort* lB = Bs + (wv * 32) * BK;

    f32x4 acc[4][4];
#pragma unroll
    for (int i = 0; i < 4; i++)
#pragma unroll
        for (int j = 0; j < 4; j++)
            acc[i][j] = (f32x4){0.f, 0.f, 0.f, 0.f};

    for (int k0 = 0; k0 < K_DIM; k0 += BK) {
#pragma unroll
        for (int i = 0; i < 4; i++)
            gld16(gA + (size_t)(i * 8) * K_DIM + k0, lA + (i * 8) * BK);
#pragma unroll
        for (int i = 0; i < 2; i++)
            gld16(gB + (size_t)(i * 16) * K_DIM + k0, lB + (i * 16) * BK);
        __syncthreads();

        short8 a[4], b[4];
#pragma unroll
        for (int nj = 0; nj < 4; nj++)
            b[nj] = *(const short8*)(Bs + (wn * 64 + nj * 16 + r) * BK + quad * 8);
#pragma unroll
        for (int mi = 0; mi < 4; mi++) {
            const float* pa = As + (wm * 64 + mi * 16 + r) * BK;
            const int g0 = ((quad * 2) ^ (r & 7)) * 4;
            const int g1 = ((quad * 2 + 1) ^ (r & 7)) * 4;
            float4 f0 = *(const float4*)(pa + g0);
            float4 f1 = *(const float4*)(pa + g1);
            union { short8 v; uint32_t u[4]; } pk;
            pk.u[0] = pack2(f0.x, f0.y);
            pk.u[1] = pack2(f0.z, f0.w);
            pk.u[2] = pack2(f1.x, f1.y);
            pk.u[3] = pack2(f1.z, f1.w);
            a[mi] = pk.v;
        }
#pragma unroll
        for (int mi = 0; mi < 4; mi++)
#pragma unroll
            for (int nj = 0; nj < 4; nj++)
                acc[mi][nj] = __builtin_amdgcn_mfma_f32_16x16x32_bf16(
                    a[mi], b[nj], acc[mi][nj], 0, 0, 0);
        __syncthreads();
    }

    float bv[4];
#pragma unroll
    for (int nj = 0; nj < 4; nj++) bv[nj] = bias[n0 + wn * 64 + nj * 16 + r];
#pragma unroll
    for (int mi = 0; mi < 4; mi++)
#pragma unroll
        for (int nj = 0; nj < 4; nj++) {
            const int col = n0 + wn * 64 + nj * 16 + r;
#pragma unroll
            for (int i = 0; i < 4; i++) {
                const int row = m0 + wm * 64 + mi * 16 + quad * 4 + i;
                out[(size_t)row * N_DIM + col] = acc[mi][nj][i] + bv[nj];
            }
        }
}

extern "C" void kernel_launch(void* const* d_in, const int* in_sizes, int n_in,
                              void* d_out, int out_size, void* d_ws, size_t ws_size,
                              hipStream_t stream) {
    const float* x = (const float*)d_in[0];
    const float* W = (const float*)d_in[1];
    const float* b = (const float*)d_in[2];
    float* out = (float*)d_out;
    double* wsd = (double*)d_ws;                       // ws[0]=thr, ws[8..263]=partials
    ushort* wt = (ushort*)((char*)d_ws + 4096);        // 2 MB ternary bf16 [O,K]
    const int M = in_sizes[0] / K_DIM;                 // 32768

    const size_t XB_OFF = 4u * 1024 * 1024;            // x_bf16 at +4 MB
    const size_t WS_NEED = XB_OFF + (size_t)M * K_DIM * sizeof(ushort);
    ushort* xb = (ushort*)((char*)d_ws + XB_OFF);

    const int n4 = (K_DIM * N_DIM) / 4;
    k_abs_partial<<<256, 256, 0, stream>>>(W, wsd + 8, n4);
    k_abs_final<<<1, 256, 0, stream>>>(wsd);
    k_quant<<<n4 / 256, 256, 0, stream>>>(W, wsd, wt, n4);

    const int nblocks = (M / BM) * (N_DIM / BN);       // 2048
    if (ws_size >= WS_NEED) {
        const int n8 = M * K_DIM / 8;
        k_cvt<<<n8 / 256, 256, 0, stream>>>(x, xb, n8);
        k_gemm_bf16<<<nblocks, 256, 0, stream>>>(xb, wt, b, out);
    } else {
        k_gemm_f32<<<nblocks, 256, 0, stream>>>(x, wt, b, out);
    }
}